// Round 14
// baseline (21.948 us; speedup 1.0000x reference)
//
#include <hip/hip_runtime.h>

typedef float f2 __attribute__((ext_vector_type(2)));
typedef float f4 __attribute__((ext_vector_type(4)));
typedef int   i4 __attribute__((ext_vector_type(4)));

#define HIDDEN 64
#define MASK_FILL -1e9f
#define EPT 4
#define TPB 256

// ---------- kernel A: fold v = W2@Ws, c = b2.Ws + bs into d_ws ----------
// ws[4*k2 + 0,1] = b1[2k2], b1[2k2+1]; ws[4*k2 + 2,3] = v[2k2], v[2k2+1];
// ws[128] = c.
__global__ __launch_bounds__(TPB) void fold_vc(
    const float* __restrict__ b1,
    const float* __restrict__ W2,
    const float* __restrict__ b2,
    const float* __restrict__ Ws,
    const float* __restrict__ bs,
    float* __restrict__ ws)
{
    const int t = threadIdx.x;
    {   // v[k] = W2[k]·Ws : 4 threads per row, f4 reads, 4-lane reduce
        const f4* W2v = reinterpret_cast<const f4*>(W2 + t * 16);
        const int j0 = 16 * (t & 3);
        float p = 0.f;
#pragma unroll
        for (int i = 0; i < 4; ++i) {
            const f4 wv = W2v[i];
            const int j = j0 + 4 * i;
            p = fmaf(wv.x, Ws[j], p);
            p = fmaf(wv.y, Ws[j + 1], p);
            p = fmaf(wv.z, Ws[j + 2], p);
            p = fmaf(wv.w, Ws[j + 3], p);
        }
        p += __shfl_xor(p, 1);
        p += __shfl_xor(p, 2);
        if ((t & 3) == 0) {
            const int k = t >> 2;
            ws[4 * (k >> 1) + 2 + (k & 1)] = p;
        }
    }
    if (t < 64) {
        ws[4 * (t >> 1) + (t & 1)] = b1[t];
    } else if (t < 128) {
        const int l = t - 64;
        float p = b2[l] * Ws[l];
#pragma unroll
        for (int off = 1; off < 64; off <<= 1) p += __shfl_xor(p, off);
        if (l == 0) ws[128] = p + bs[0];
    }
}

// ---------- kernel B: barrier-free main (NO __shared__, NO __syncthreads) ----------
// All weights via wave-uniform global reads -> s_load (K$). Waves never
// synchronize -> natural phase drift lets VALU phases cover mem phases
// (round-8/12 probes showed mem 8us + compute 6.5us running back-to-back;
// the block barrier was the suspected synchronizer).
__global__ __launch_bounds__(TPB) void edge_score_main(
    const float* __restrict__ x,
    const int* __restrict__ edge_index,
    const float* __restrict__ edge_attr,
    const int* __restrict__ edge_mask,
    const float* __restrict__ W1,
    const float* __restrict__ ws,       // folded (b,v) pairs + c
    float* __restrict__ out, int E)
{
    const int tid = blockIdx.x * TPB + threadIdx.x;
    const int e = tid * EPT;
    if (e >= E) return;

    const i4 rows = *reinterpret_cast<const i4*>(edge_index + e);
    const i4 cols = *reinterpret_cast<const i4*>(edge_index + E + e);
    const i4 mk   = *reinterpret_cast<const i4*>(edge_mask + e);
    const f4 eaA  = *reinterpret_cast<const f4*>(edge_attr + 2 * e);
    const f4 eaB  = *reinterpret_cast<const f4*>(edge_attr + 2 * e + 4);

    const f2 xr0 = {x[rows.x], x[rows.x]}, xr1 = {x[rows.y], x[rows.y]},
             xr2 = {x[rows.z], x[rows.z]}, xr3 = {x[rows.w], x[rows.w]};
    const f2 xc0 = {x[cols.x], x[cols.x]}, xc1 = {x[cols.y], x[cols.y]},
             xc2 = {x[cols.z], x[cols.z]}, xc3 = {x[cols.w], x[cols.w]};
    const f2 e00 = {eaA.x, eaA.x}, e10 = {eaA.y, eaA.y};
    const f2 e01 = {eaA.z, eaA.z}, e11 = {eaA.w, eaA.w};
    const f2 e02 = {eaB.x, eaB.x}, e12 = {eaB.y, eaB.y};
    const f2 e03 = {eaB.z, eaB.z}, e13 = {eaB.w, eaB.w};

    const float c = ws[128];
    const f2 z2 = {0.f, 0.f};
    f2 a0 = {c, 0.f}, a1 = {c, 0.f}, a2 = {c, 0.f}, a3 = {c, 0.f};

#pragma unroll 4
    for (int k2 = 0; k2 < 32; ++k2) {
        // all wave-uniform -> s_load from K$
        const f2 w0 = {W1[2 * k2],       W1[2 * k2 + 1]};
        const f2 w1 = {W1[64 + 2 * k2],  W1[64 + 2 * k2 + 1]};
        const f2 w2 = {W1[128 + 2 * k2], W1[128 + 2 * k2 + 1]};
        const f2 w3 = {W1[192 + 2 * k2], W1[192 + 2 * k2 + 1]};
        const f4 C = *reinterpret_cast<const f4*>(ws + 4 * k2);
        const f2 bb = {C.x, C.y}, vv = {C.z, C.w};

        f2 h0 = __builtin_elementwise_fma(xr0, w0, __builtin_elementwise_fma(xc0, w1,
                __builtin_elementwise_fma(e00, w2, __builtin_elementwise_fma(e10, w3, bb))));
        f2 h1 = __builtin_elementwise_fma(xr1, w0, __builtin_elementwise_fma(xc1, w1,
                __builtin_elementwise_fma(e01, w2, __builtin_elementwise_fma(e11, w3, bb))));
        f2 h2 = __builtin_elementwise_fma(xr2, w0, __builtin_elementwise_fma(xc2, w1,
                __builtin_elementwise_fma(e02, w2, __builtin_elementwise_fma(e12, w3, bb))));
        f2 h3 = __builtin_elementwise_fma(xr3, w0, __builtin_elementwise_fma(xc3, w1,
                __builtin_elementwise_fma(e03, w2, __builtin_elementwise_fma(e13, w3, bb))));
        a0 = __builtin_elementwise_fma(__builtin_elementwise_max(h0, z2), vv, a0);
        a1 = __builtin_elementwise_fma(__builtin_elementwise_max(h1, z2), vv, a1);
        a2 = __builtin_elementwise_fma(__builtin_elementwise_max(h2, z2), vv, a2);
        a3 = __builtin_elementwise_fma(__builtin_elementwise_max(h3, z2), vv, a3);
    }

    f4 res;
    res.x = mk.x ? (a0.x + a0.y) : MASK_FILL;
    res.y = mk.y ? (a1.x + a1.y) : MASK_FILL;
    res.z = mk.z ? (a2.x + a2.y) : MASK_FILL;
    res.w = mk.w ? (a3.x + a3.y) : MASK_FILL;
    *reinterpret_cast<f4*>(out + e) = res;
}

extern "C" void kernel_launch(void* const* d_in, const int* in_sizes, int n_in,
                              void* d_out, int out_size, void* d_ws, size_t ws_size,
                              hipStream_t stream) {
    const float* x          = (const float*)d_in[0];
    const int*   edge_index = (const int*)d_in[1];
    const float* edge_attr  = (const float*)d_in[2];
    const int*   edge_mask  = (const int*)d_in[3];
    const float* W1 = (const float*)d_in[4];
    const float* b1 = (const float*)d_in[5];
    const float* W2 = (const float*)d_in[6];
    const float* b2 = (const float*)d_in[7];
    const float* Ws = (const float*)d_in[8];
    const float* bs = (const float*)d_in[9];
    float* out = (float*)d_out;
    float* ws  = (float*)d_ws;

    const int E = out_size;  // 1,000,000
    const int work = (E + EPT - 1) / EPT;
    const int blocks = (work + TPB - 1) / TPB;   // 977

    fold_vc<<<1, TPB, 0, stream>>>(b1, W2, b2, Ws, bs, ws);
    edge_score_main<<<blocks, TPB, 0, stream>>>(
        x, edge_index, edge_attr, edge_mask, W1, ws, out, E);
}

// Round 15
// 18.753 us; speedup vs baseline: 1.1704x; 1.1704x over previous
//
#include <hip/hip_runtime.h>

typedef float f4 __attribute__((ext_vector_type(4)));
typedef int   i4 __attribute__((ext_vector_type(4)));
typedef int   i2 __attribute__((ext_vector_type(2)));
typedef _Float16 h2 __attribute__((ext_vector_type(2)));

#define MASK_FILL -1e9f
#define EPT 4
#define TPB 256

static __device__ __forceinline__ float dot2acc(h2 a, h2 b, float c) {
#if __has_builtin(__builtin_amdgcn_fdot2)
    return __builtin_amdgcn_fdot2(a, b, c, false);
#else
    return c + (float)a.x * (float)b.x + (float)a.y * (float)b.y;
#endif
}

// scores = relu([x[row], x[col], edge_attr] @ W1 + b1) . v + c
// Round 15: k-loop in packed f16 (v_pk_fma_f16 / v_pk_max_f16 /
// v_dot2_f32_f16) -- guaranteed-packed VALU, vs f32 "f2" ops whose packed
// lowering is unreliable (no v_pk_max_f32 exists). Round-10 VALUBusy=50%
// implies VALU ~6.5us/copy, 2.7x the packed-f32 model => suspect silent
// scalarization. mem path byte-identical to round-9 best.
__global__ __launch_bounds__(TPB) void edge_score_fused(
    const float* __restrict__ x,                 // [N,1]
    const int* __restrict__ edge_index,          // [2,E] int32
    const float* __restrict__ edge_attr,         // [E,2]
    const int* __restrict__ edge_mask,           // [E] int32
    const float* __restrict__ W1,                // [4,64]
    const float* __restrict__ b1,                // [64]
    const float* __restrict__ W2,                // [64,64]
    const float* __restrict__ b2,                // [64]
    const float* __restrict__ Ws,                // [64,1]
    const float* __restrict__ bs,                // [1]
    float* __restrict__ out, int E)
{
    __shared__ __align__(16) unsigned wU[32][4];  // [k2] {w0pk,w1pk,w2pk,w3pk} f16x2
    __shared__ __align__(8)  unsigned bvU[32][2]; // [k2] {bpk, vpk} f16x2
    __shared__ float vF[64];
    __shared__ float cS;

    const int t = threadIdx.x;

    // ---- fold v = W2@Ws (all threads, 4/row), c = b2.Ws+bs (wave 1) ----
    {
        const f4* W2v = reinterpret_cast<const f4*>(W2 + t * 16);
        const int j0 = 16 * (t & 3);
        float p = 0.f;
#pragma unroll
        for (int i = 0; i < 4; ++i) {
            const f4 wv = W2v[i];
            const int j = j0 + 4 * i;
            p = fmaf(wv.x, Ws[j], p);
            p = fmaf(wv.y, Ws[j + 1], p);
            p = fmaf(wv.z, Ws[j + 2], p);
            p = fmaf(wv.w, Ws[j + 3], p);
        }
        p += __shfl_xor(p, 1);
        p += __shfl_xor(p, 2);
        if ((t & 3) == 0) vF[t >> 2] = p;
    }
    if (t >= 64 && t < 128) {
        const int l = t - 64;
        float p = b2[l] * Ws[l];
#pragma unroll
        for (int off = 1; off < 64; off <<= 1) p += __shfl_xor(p, off);
        if (l == 0) cS = p + bs[0];
    }
    __syncthreads();

    // ---- pack weights to f16x2 (threads 0..31, one k-pair each) ----
    if (t < 32) {
        const int k = 2 * t;
        wU[t][0] = __builtin_bit_cast(unsigned, (h2){(_Float16)W1[k],       (_Float16)W1[k + 1]});
        wU[t][1] = __builtin_bit_cast(unsigned, (h2){(_Float16)W1[64 + k],  (_Float16)W1[64 + k + 1]});
        wU[t][2] = __builtin_bit_cast(unsigned, (h2){(_Float16)W1[128 + k], (_Float16)W1[128 + k + 1]});
        wU[t][3] = __builtin_bit_cast(unsigned, (h2){(_Float16)W1[192 + k], (_Float16)W1[192 + k + 1]});
        bvU[t][0] = __builtin_bit_cast(unsigned, (h2){(_Float16)b1[k], (_Float16)b1[k + 1]});
        bvU[t][1] = __builtin_bit_cast(unsigned, (h2){(_Float16)vF[k], (_Float16)vF[k + 1]});
    }
    __syncthreads();

    // ---- main: 4 edges / thread (streams + gathers identical to round 9) ----
    const int tid = blockIdx.x * TPB + t;
    const int e = tid * EPT;
    if (e >= E) return;  // E % 4 == 0

    const i4 rows = *reinterpret_cast<const i4*>(edge_index + e);
    const i4 cols = *reinterpret_cast<const i4*>(edge_index + E + e);
    const i4 mk   = *reinterpret_cast<const i4*>(edge_mask + e);
    const f4 eaA  = *reinterpret_cast<const f4*>(edge_attr + 2 * e);
    const f4 eaB  = *reinterpret_cast<const f4*>(edge_attr + 2 * e + 4);

    const float g0 = x[rows.x], g1 = x[rows.y], g2 = x[rows.z], g3 = x[rows.w];
    const float p0 = x[cols.x], p1 = x[cols.y], p2 = x[cols.z], p3 = x[cols.w];

    const h2 xr0 = {(_Float16)g0, (_Float16)g0}, xr1 = {(_Float16)g1, (_Float16)g1},
             xr2 = {(_Float16)g2, (_Float16)g2}, xr3 = {(_Float16)g3, (_Float16)g3};
    const h2 xc0 = {(_Float16)p0, (_Float16)p0}, xc1 = {(_Float16)p1, (_Float16)p1},
             xc2 = {(_Float16)p2, (_Float16)p2}, xc3 = {(_Float16)p3, (_Float16)p3};
    const h2 e00 = {(_Float16)eaA.x, (_Float16)eaA.x}, e10 = {(_Float16)eaA.y, (_Float16)eaA.y};
    const h2 e01 = {(_Float16)eaA.z, (_Float16)eaA.z}, e11 = {(_Float16)eaA.w, (_Float16)eaA.w};
    const h2 e02 = {(_Float16)eaB.x, (_Float16)eaB.x}, e12 = {(_Float16)eaB.y, (_Float16)eaB.y};
    const h2 e03 = {(_Float16)eaB.z, (_Float16)eaB.z}, e13 = {(_Float16)eaB.w, (_Float16)eaB.w};

    const float c = cS;
    float a0 = c, a1 = c, a2 = c, a3 = c;
    const h2 z2 = {(_Float16)0.f, (_Float16)0.f};

#pragma unroll 4
    for (int k2 = 0; k2 < 32; ++k2) {
        const i4 Wi = *reinterpret_cast<const i4*>(&wU[k2][0]);   // ds_read_b128
        const i2 Bi = *reinterpret_cast<const i2*>(&bvU[k2][0]);  // ds_read_b64
        const h2 w0 = __builtin_bit_cast(h2, Wi.x);
        const h2 w1 = __builtin_bit_cast(h2, Wi.y);
        const h2 w2 = __builtin_bit_cast(h2, Wi.z);
        const h2 w3 = __builtin_bit_cast(h2, Wi.w);
        const h2 bb = __builtin_bit_cast(h2, Bi.x);
        const h2 vv = __builtin_bit_cast(h2, Bi.y);

        h2 q0 = __builtin_elementwise_fma(xr0, w0, __builtin_elementwise_fma(xc0, w1,
                __builtin_elementwise_fma(e00, w2, __builtin_elementwise_fma(e10, w3, bb))));
        h2 q1 = __builtin_elementwise_fma(xr1, w0, __builtin_elementwise_fma(xc1, w1,
                __builtin_elementwise_fma(e01, w2, __builtin_elementwise_fma(e11, w3, bb))));
        h2 q2 = __builtin_elementwise_fma(xr2, w0, __builtin_elementwise_fma(xc2, w1,
                __builtin_elementwise_fma(e02, w2, __builtin_elementwise_fma(e12, w3, bb))));
        h2 q3 = __builtin_elementwise_fma(xr3, w0, __builtin_elementwise_fma(xc3, w1,
                __builtin_elementwise_fma(e03, w2, __builtin_elementwise_fma(e13, w3, bb))));
        q0 = __builtin_elementwise_max(q0, z2);
        q1 = __builtin_elementwise_max(q1, z2);
        q2 = __builtin_elementwise_max(q2, z2);
        q3 = __builtin_elementwise_max(q3, z2);
        a0 = dot2acc(q0, vv, a0);
        a1 = dot2acc(q1, vv, a1);
        a2 = dot2acc(q2, vv, a2);
        a3 = dot2acc(q3, vv, a3);
    }

    f4 res;
    res.x = mk.x ? a0 : MASK_FILL;
    res.y = mk.y ? a1 : MASK_FILL;
    res.z = mk.z ? a2 : MASK_FILL;
    res.w = mk.w ? a3 : MASK_FILL;
    *reinterpret_cast<f4*>(out + e) = res;
}

extern "C" void kernel_launch(void* const* d_in, const int* in_sizes, int n_in,
                              void* d_out, int out_size, void* d_ws, size_t ws_size,
                              hipStream_t stream) {
    const float* x          = (const float*)d_in[0];
    const int*   edge_index = (const int*)d_in[1];
    const float* edge_attr  = (const float*)d_in[2];
    const int*   edge_mask  = (const int*)d_in[3];
    const float* W1 = (const float*)d_in[4];
    const float* b1 = (const float*)d_in[5];
    const float* W2 = (const float*)d_in[6];
    const float* b2 = (const float*)d_in[7];
    const float* Ws = (const float*)d_in[8];
    const float* bs = (const float*)d_in[9];
    float* out = (float*)d_out;

    const int E = out_size;  // 1,000,000
    const int work = (E + EPT - 1) / EPT;
    const int blocks = (work + TPB - 1) / TPB;   // 977
    edge_score_fused<<<blocks, TPB, 0, stream>>>(
        x, edge_index, edge_attr, edge_mask, W1, b1, W2, b2, Ws, bs, out, E);
}

// Round 16
// 18.620 us; speedup vs baseline: 1.1787x; 1.0071x over previous
//
#include <hip/hip_runtime.h>

typedef float f4 __attribute__((ext_vector_type(4)));
typedef int   i4 __attribute__((ext_vector_type(4)));
typedef int   i2 __attribute__((ext_vector_type(2)));
typedef _Float16 h2 __attribute__((ext_vector_type(2)));

#define MASK_FILL -1e9f
#define EPT 4
#define TPB 256

static __device__ __forceinline__ float dot2acc(h2 a, h2 b, float c) {
#if __has_builtin(__builtin_amdgcn_fdot2)
    return __builtin_amdgcn_fdot2(a, b, c, false);
#else
    return c + (float)a.x * (float)b.x + (float)a.y * (float)b.y;
#endif
}

// scores = relu([x[row], x[col], edge_attr] @ W1 + b1) . v + c
// Round 16: r15 (f16-packed k-loop, best 18.75us) + MASK-PREDICATED gathers.
// ~50% of edges are masked; their x-gathers are discarded. `mk ? x[i] : 0`
// forces exec-masked loads -> inactive lanes issue NO TA/L1/L2 requests,
// halving random-gather traffic (the suspected 8us mem-path excess).
__global__ __launch_bounds__(TPB) void edge_score_fused(
    const float* __restrict__ x,                 // [N,1]
    const int* __restrict__ edge_index,          // [2,E] int32
    const float* __restrict__ edge_attr,         // [E,2]
    const int* __restrict__ edge_mask,           // [E] int32
    const float* __restrict__ W1,                // [4,64]
    const float* __restrict__ b1,                // [64]
    const float* __restrict__ W2,                // [64,64]
    const float* __restrict__ b2,                // [64]
    const float* __restrict__ Ws,                // [64,1]
    const float* __restrict__ bs,                // [1]
    float* __restrict__ out, int E)
{
    __shared__ __align__(16) unsigned wU[32][4];  // [k2] {w0pk,w1pk,w2pk,w3pk} f16x2
    __shared__ __align__(8)  unsigned bvU[32][2]; // [k2] {bpk, vpk} f16x2
    __shared__ float vF[64];
    __shared__ float cS;

    const int t = threadIdx.x;

    // ---- fold v = W2@Ws (all threads, 4/row), c = b2.Ws+bs (wave 1) ----
    {
        const f4* W2v = reinterpret_cast<const f4*>(W2 + t * 16);
        const int j0 = 16 * (t & 3);
        float p = 0.f;
#pragma unroll
        for (int i = 0; i < 4; ++i) {
            const f4 wv = W2v[i];
            const int j = j0 + 4 * i;
            p = fmaf(wv.x, Ws[j], p);
            p = fmaf(wv.y, Ws[j + 1], p);
            p = fmaf(wv.z, Ws[j + 2], p);
            p = fmaf(wv.w, Ws[j + 3], p);
        }
        p += __shfl_xor(p, 1);
        p += __shfl_xor(p, 2);
        if ((t & 3) == 0) vF[t >> 2] = p;
    }
    if (t >= 64 && t < 128) {
        const int l = t - 64;
        float p = b2[l] * Ws[l];
#pragma unroll
        for (int off = 1; off < 64; off <<= 1) p += __shfl_xor(p, off);
        if (l == 0) cS = p + bs[0];
    }
    __syncthreads();

    // ---- pack weights to f16x2 (threads 0..31, one k-pair each) ----
    if (t < 32) {
        const int k = 2 * t;
        wU[t][0] = __builtin_bit_cast(unsigned, (h2){(_Float16)W1[k],       (_Float16)W1[k + 1]});
        wU[t][1] = __builtin_bit_cast(unsigned, (h2){(_Float16)W1[64 + k],  (_Float16)W1[64 + k + 1]});
        wU[t][2] = __builtin_bit_cast(unsigned, (h2){(_Float16)W1[128 + k], (_Float16)W1[128 + k + 1]});
        wU[t][3] = __builtin_bit_cast(unsigned, (h2){(_Float16)W1[192 + k], (_Float16)W1[192 + k + 1]});
        bvU[t][0] = __builtin_bit_cast(unsigned, (h2){(_Float16)b1[k], (_Float16)b1[k + 1]});
        bvU[t][1] = __builtin_bit_cast(unsigned, (h2){(_Float16)vF[k], (_Float16)vF[k + 1]});
    }
    __syncthreads();

    // ---- main: 4 edges / thread ----
    const int tid = blockIdx.x * TPB + t;
    const int e = tid * EPT;
    if (e >= E) return;  // E % 4 == 0

    const i4 rows = *reinterpret_cast<const i4*>(edge_index + e);
    const i4 cols = *reinterpret_cast<const i4*>(edge_index + E + e);
    const i4 mk   = *reinterpret_cast<const i4*>(edge_mask + e);
    const f4 eaA  = *reinterpret_cast<const f4*>(edge_attr + 2 * e);
    const f4 eaB  = *reinterpret_cast<const f4*>(edge_attr + 2 * e + 4);

    // mask-predicated gathers: masked edges' values are never used ->
    // exec-masked loads issue no memory requests for ~50% of lanes.
    const float g0 = mk.x ? x[rows.x] : 0.f;
    const float g1 = mk.y ? x[rows.y] : 0.f;
    const float g2 = mk.z ? x[rows.z] : 0.f;
    const float g3 = mk.w ? x[rows.w] : 0.f;
    const float p0 = mk.x ? x[cols.x] : 0.f;
    const float p1 = mk.y ? x[cols.y] : 0.f;
    const float p2 = mk.z ? x[cols.z] : 0.f;
    const float p3 = mk.w ? x[cols.w] : 0.f;

    const h2 xr0 = {(_Float16)g0, (_Float16)g0}, xr1 = {(_Float16)g1, (_Float16)g1},
             xr2 = {(_Float16)g2, (_Float16)g2}, xr3 = {(_Float16)g3, (_Float16)g3};
    const h2 xc0 = {(_Float16)p0, (_Float16)p0}, xc1 = {(_Float16)p1, (_Float16)p1},
             xc2 = {(_Float16)p2, (_Float16)p2}, xc3 = {(_Float16)p3, (_Float16)p3};
    const h2 e00 = {(_Float16)eaA.x, (_Float16)eaA.x}, e10 = {(_Float16)eaA.y, (_Float16)eaA.y};
    const h2 e01 = {(_Float16)eaA.z, (_Float16)eaA.z}, e11 = {(_Float16)eaA.w, (_Float16)eaA.w};
    const h2 e02 = {(_Float16)eaB.x, (_Float16)eaB.x}, e12 = {(_Float16)eaB.y, (_Float16)eaB.y};
    const h2 e03 = {(_Float16)eaB.z, (_Float16)eaB.z}, e13 = {(_Float16)eaB.w, (_Float16)eaB.w};

    const float c = cS;
    float a0 = c, a1 = c, a2 = c, a3 = c;
    const h2 z2 = {(_Float16)0.f, (_Float16)0.f};

#pragma unroll 4
    for (int k2 = 0; k2 < 32; ++k2) {
        const i4 Wi = *reinterpret_cast<const i4*>(&wU[k2][0]);   // ds_read_b128
        const i2 Bi = *reinterpret_cast<const i2*>(&bvU[k2][0]);  // ds_read_b64
        const h2 w0 = __builtin_bit_cast(h2, Wi.x);
        const h2 w1 = __builtin_bit_cast(h2, Wi.y);
        const h2 w2 = __builtin_bit_cast(h2, Wi.z);
        const h2 w3 = __builtin_bit_cast(h2, Wi.w);
        const h2 bb = __builtin_bit_cast(h2, Bi.x);
        const h2 vv = __builtin_bit_cast(h2, Bi.y);

        h2 q0 = __builtin_elementwise_fma(xr0, w0, __builtin_elementwise_fma(xc0, w1,
                __builtin_elementwise_fma(e00, w2, __builtin_elementwise_fma(e10, w3, bb))));
        h2 q1 = __builtin_elementwise_fma(xr1, w0, __builtin_elementwise_fma(xc1, w1,
                __builtin_elementwise_fma(e01, w2, __builtin_elementwise_fma(e11, w3, bb))));
        h2 q2 = __builtin_elementwise_fma(xr2, w0, __builtin_elementwise_fma(xc2, w1,
                __builtin_elementwise_fma(e02, w2, __builtin_elementwise_fma(e12, w3, bb))));
        h2 q3 = __builtin_elementwise_fma(xr3, w0, __builtin_elementwise_fma(xc3, w1,
                __builtin_elementwise_fma(e03, w2, __builtin_elementwise_fma(e13, w3, bb))));
        q0 = __builtin_elementwise_max(q0, z2);
        q1 = __builtin_elementwise_max(q1, z2);
        q2 = __builtin_elementwise_max(q2, z2);
        q3 = __builtin_elementwise_max(q3, z2);
        a0 = dot2acc(q0, vv, a0);
        a1 = dot2acc(q1, vv, a1);
        a2 = dot2acc(q2, vv, a2);
        a3 = dot2acc(q3, vv, a3);
    }

    f4 res;
    res.x = mk.x ? a0 : MASK_FILL;
    res.y = mk.y ? a1 : MASK_FILL;
    res.z = mk.z ? a2 : MASK_FILL;
    res.w = mk.w ? a3 : MASK_FILL;
    *reinterpret_cast<f4*>(out + e) = res;
}

extern "C" void kernel_launch(void* const* d_in, const int* in_sizes, int n_in,
                              void* d_out, int out_size, void* d_ws, size_t ws_size,
                              hipStream_t stream) {
    const float* x          = (const float*)d_in[0];
    const int*   edge_index = (const int*)d_in[1];
    const float* edge_attr  = (const float*)d_in[2];
    const int*   edge_mask  = (const int*)d_in[3];
    const float* W1 = (const float*)d_in[4];
    const float* b1 = (const float*)d_in[5];
    const float* W2 = (const float*)d_in[6];
    const float* b2 = (const float*)d_in[7];
    const float* Ws = (const float*)d_in[8];
    const float* bs = (const float*)d_in[9];
    float* out = (float*)d_out;

    const int E = out_size;  // 1,000,000
    const int work = (E + EPT - 1) / EPT;
    const int blocks = (work + TPB - 1) / TPB;   // 977
    edge_score_fused<<<blocks, TPB, 0, stream>>>(
        x, edge_index, edge_attr, edge_mask, W1, b1, W2, b2, Ws, bs, out, E);
}